// Round 11
// baseline (3562.188 us; speedup 1.0000x reference)
//
#include <hip/hip_runtime.h>
#include <stdint.h>

typedef __attribute__((ext_vector_type(4))) float f32x4;
typedef __attribute__((ext_vector_type(8))) short bf16x8;
typedef __attribute__((ext_vector_type(4))) unsigned int u32x4;
typedef __attribute__((ext_vector_type(2))) unsigned int u32x2;
typedef __attribute__((ext_vector_type(4))) unsigned short u16x4;
typedef unsigned short ushort_t;

#define B_N 32
#define T_N 1024
#define D_N 512
#define H_N 512
#define G4H 2048

__device__ __forceinline__ ushort_t f2bf(float f) {
    union { float f; unsigned int u; } v; v.f = f;
    unsigned int r = v.u + 0x7FFFu + ((v.u >> 16) & 1u);   // RNE
    return (ushort_t)(r >> 16);
}
__device__ __forceinline__ float bf2f(ushort_t b) {
    union { unsigned int u; float f; } v; v.u = ((unsigned int)b) << 16;
    return v.f;
}
// fast sigmoid/tanh via v_exp_f32 + v_rcp_f32 (~1e-6 rel err << bf16 eps)
__device__ __forceinline__ float fsig(float x) {
    return __builtin_amdgcn_rcpf(1.f + __expf(-x));
}
__device__ __forceinline__ float ftanh(float x) {
    return 1.f - 2.f * __builtin_amdgcn_rcpf(1.f + __expf(2.f * x));
}

// ---------------------------------------------------------------------------
// prep: fp32 -> bf16 of W_ih, W_hh; bias_sum; zero tagged ring EVERY launch
// (ws persists across graph replays; stale tags would corrupt this run).
// ---------------------------------------------------------------------------
__global__ __launch_bounds__(256) void prep_kernel(
    const float* __restrict__ wih, const float* __restrict__ whh,
    const float* __restrict__ bih, const float* __restrict__ bhh,
    ushort_t* __restrict__ wihb, ushort_t* __restrict__ whhb,
    float* __restrict__ bias, unsigned int* __restrict__ ringu)
{
    size_t i = (size_t)blockIdx.x * 256 + threadIdx.x;
    if (i < 2048) bias[i] = bih[i] + bhh[i];
    if (i < 32768) ringu[i] = 0u;                    // tag 0 = never valid
    const size_t NW = (size_t)G4H * D_N / 4;         // 262144 quads
    if (i < NW) {
        f32x4 v = ((const f32x4*)wih)[i];
        u16x4 o; o[0]=f2bf(v[0]); o[1]=f2bf(v[1]); o[2]=f2bf(v[2]); o[3]=f2bf(v[3]);
        ((u16x4*)wihb)[i] = o;
    } else if (i < 2 * NW) {
        size_t j = i - NW;
        f32x4 v = ((const f32x4*)whh)[j];
        u16x4 o; o[0]=f2bf(v[0]); o[1]=f2bf(v[1]); o[2]=f2bf(v[2]); o[3]=f2bf(v[3]);
        ((u16x4*)whhb)[j] = o;
    }
}

// ---------------------------------------------------------------------------
// xg = x @ W_ih^T + (b_ih+b_hh), stored bf16 as [T][B][4H]. (unchanged R10)
// ---------------------------------------------------------------------------
__global__ __launch_bounds__(512, 1) void xg_gemm(
    const float* __restrict__ x,        // [B][T][D] fp32
    const ushort_t* __restrict__ wihb,  // [4H][D] bf16
    const float* __restrict__ bias,     // [4H]
    ushort_t* __restrict__ xg)          // [T][B][4H] bf16
{
    const int tc = blockIdx.x >> 3;     // 0..63  (t-chunk of 16)
    const int gb = blockIdx.x & 7;      // 0..7   (gate-chunk of 256)
    const int tid = threadIdx.x;
    const int w = tid >> 6, l = tid & 63, lr = l & 15, lk = l >> 4;

    __shared__ ushort_t xs[16 * 520];   // 16 t-rows x 512 d (+8 pad) bf16

    const int r0 = gb * 256 + w * 16;
    const int r1 = r0 + 128;
    bf16x8 a0[16], a1[16];
#pragma unroll
    for (int kk = 0; kk < 16; ++kk) {
        a0[kk] = *(const bf16x8*)(wihb + (size_t)(r0 + lr) * D_N + kk * 32 + lk * 8);
        a1[kk] = *(const bf16x8*)(wihb + (size_t)(r1 + lr) * D_N + kk * 32 + lk * 8);
    }
    float bs0[4], bs1[4];
#pragma unroll
    for (int j = 0; j < 4; ++j) {
        bs0[j] = bias[r0 + lk * 4 + j];
        bs1[j] = bias[r1 + lk * 4 + j];
    }

    const int srow = tid >> 5;          // 0..15 (staging row = t-offset)
    const int sq   = tid & 31;          // 0..31

    for (int b = 0; b < B_N; ++b) {
        const float* xr = x + ((size_t)b * T_N + tc * 16 + srow) * D_N;
#pragma unroll
        for (int c = 0; c < 4; ++c) {
            f32x4 v = *(const f32x4*)(xr + c * 128 + sq * 4);
            u16x4 o; o[0]=f2bf(v[0]); o[1]=f2bf(v[1]); o[2]=f2bf(v[2]); o[3]=f2bf(v[3]);
            *(u16x4*)(xs + srow * 520 + c * 128 + sq * 4) = o;
        }
        __syncthreads();

        f32x4 c0, c1;
#pragma unroll
        for (int j = 0; j < 4; ++j) { c0[j] = 0.f; c1[j] = 0.f; }
#pragma unroll
        for (int kk = 0; kk < 16; ++kk) {
            bf16x8 bf = *(const bf16x8*)((const char*)xs + lr * 1040 + kk * 64 + lk * 16);
            c0 = __builtin_amdgcn_mfma_f32_16x16x32_bf16(a0[kk], bf, c0, 0, 0, 0);
            c1 = __builtin_amdgcn_mfma_f32_16x16x32_bf16(a1[kk], bf, c1, 0, 0, 0);
        }

        const int t = tc * 16 + lr;
        ushort_t* op = xg + (size_t)t * (B_N * G4H) + (size_t)b * G4H;
        u16x4 o0, o1;
#pragma unroll
        for (int j = 0; j < 4; ++j) {
            o0[j] = f2bf(c0[j] + bs0[j]);
            o1[j] = f2bf(c1[j] + bs1[j]);
        }
        *(u16x4*)(op + r0 + lk * 4) = o0;
        *(u16x4*)(op + r1 + lk * 4) = o1;
        __syncthreads();   // protect LDS before next stage
    }
}

// ---------------------------------------------------------------------------
// Sequential LSTM recurrence — R10 structure (tagged ring, poller wave,
// in-wave gate exchange) with two changes:
//  1. EARLY POLL ISSUE (T14 pattern): the poll loads for step t+1 (and the
//     xg loads) are issued at the BOTTOM of step t, right after publish.
//     They fly while the block finishes its cell/publish tail, so at t+1's
//     top a bare vmcnt(0) + tag-check often succeeds on attempt 1 (detect
//     = V + ~1 RT instead of V + 1.5-2 RT). Fail -> proven blocking retry.
//  2. 4 MFMA accumulator chains (was 2): dep-chain latency halved.
// ---------------------------------------------------------------------------
__global__ __launch_bounds__(512, 1) void lstm_rec(
    const ushort_t* __restrict__ xg,    // [T][B][4H] bf16 (bias folded)
    const ushort_t* __restrict__ whhb,  // [4H][H] bf16
    unsigned int* __restrict__ ringu,   // [8 grp][2 par][4 batch][512 col] u32
    float* __restrict__ out,            // [B][T][H]
    float* __restrict__ hn,             // [B][H]
    float* __restrict__ cn)             // [B][H]
{
    const int tid = threadIdx.x;
    const int g = blockIdx.x >> 4;
    const int s = blockIdx.x & 15;
    const int w = tid >> 6, l = tid & 63, lr = l & 15, lk = l >> 4;

    __shared__ ushort_t hstage[4][544];   // packed h(t-1); row stride 1088 B

    // ---- persistent W_hh fragments (B operand)
    const int col4 = s * 32 + w * 4;               // this wave's 4 h-cols
    const int gc = (lr >> 2) * 512 + col4 + (lr & 3);
    bf16x8 wfrag[16];
#pragma unroll
    for (int kk = 0; kk < 16; ++kk)
        wfrag[kk] = *(const bf16x8*)(whhb + (size_t)gc * H_N + kk * 32 + lk * 8);

    float c_reg[4] = {0.f, 0.f, 0.f, 0.f};
    unsigned int* ringg = ringu + g * 4096;
    const ushort_t* xgp = xg + (size_t)(g * 4) * G4H + gc;   // + t*B*4H

    // loop-carried: poll payload (issued at bottom, checked at top) + xg words
    u32x4 a[8];
    ushort_t xw[4];
#pragma unroll
    for (int j = 0; j < 4; ++j) xw[j] = xgp[(size_t)j * G4H];   // xg(t=0)

    for (int t = 0; t < T_N; ++t) {
        f32x4 acc0, acc1, acc2, acc3;
#pragma unroll
        for (int j = 0; j < 4; ++j) {
            acc0[j] = bf2f(xw[j]);
            acc1[j] = 0.f; acc2[j] = 0.f; acc3[j] = 0.f;
        }

        if (t > 0) {
            if (tid < 64) {
                // ---- wait on the EARLY-ISSUED poll set, check tags
                asm volatile("s_waitcnt vmcnt(0)"
                             : "+v"(a[0]), "+v"(a[1]), "+v"(a[2]), "+v"(a[3]),
                               "+v"(a[4]), "+v"(a[5]), "+v"(a[6]), "+v"(a[7])
                             :: "memory");
                const unsigned int tp = ((unsigned int)t) << 16;
                unsigned int d = 0;
#pragma unroll
                for (int r = 0; r < 8; ++r) {
                    d |= (a[r][0] ^ tp); d |= (a[r][1] ^ tp);
                    d |= (a[r][2] ^ tp); d |= (a[r][3] ^ tp);
                }
                int ok = ((d & 0xFFFF0000u) == 0u);
                if (!__all(ok)) {
                    // ---- blocking retry (proven R7/R10 path)
                    const unsigned int* pp0 = ringg + ((t - 1) & 1) * 2048 + l * 8;
                    const unsigned int* pp1 = pp0 + 1024;
                    int guard = 0;
                    for (;;) {
                        __builtin_amdgcn_s_sleep(1);
                        asm volatile(
                            "global_load_dwordx4 %0, %8, off sc0 sc1\n\t"
                            "global_load_dwordx4 %1, %8, off offset:16 sc0 sc1\n\t"
                            "global_load_dwordx4 %2, %8, off offset:2048 sc0 sc1\n\t"
                            "global_load_dwordx4 %3, %8, off offset:2064 sc0 sc1\n\t"
                            "global_load_dwordx4 %4, %9, off sc0 sc1\n\t"
                            "global_load_dwordx4 %5, %9, off offset:16 sc0 sc1\n\t"
                            "global_load_dwordx4 %6, %9, off offset:2048 sc0 sc1\n\t"
                            "global_load_dwordx4 %7, %9, off offset:2064 sc0 sc1\n\t"
                            "s_waitcnt vmcnt(0)"
                            : "=&v"(a[0]), "=&v"(a[1]), "=&v"(a[2]), "=&v"(a[3]),
                              "=&v"(a[4]), "=&v"(a[5]), "=&v"(a[6]), "=&v"(a[7])
                            : "v"(pp0), "v"(pp1)
                            : "memory");
                        d = 0;
#pragma unroll
                        for (int r = 0; r < 8; ++r) {
                            d |= (a[r][0] ^ tp); d |= (a[r][1] ^ tp);
                            d |= (a[r][2] ^ tp); d |= (a[r][3] ^ tp);
                        }
                        ok = ((d & 0xFFFF0000u) == 0u);
                        if (__all(ok) || ++guard > (1 << 16)) break;
                    }
                }
                // ---- pack + stage (wave-contiguous ds_write_b128)
#pragma unroll
                for (int n = 0; n < 4; ++n) {
                    u32x4 p;
                    p[0] = __builtin_amdgcn_perm(a[2*n][1], a[2*n][0], 0x05040100u);
                    p[1] = __builtin_amdgcn_perm(a[2*n][3], a[2*n][2], 0x05040100u);
                    p[2] = __builtin_amdgcn_perm(a[2*n+1][1], a[2*n+1][0], 0x05040100u);
                    p[3] = __builtin_amdgcn_perm(a[2*n+1][3], a[2*n+1][2], 0x05040100u);
                    *(u32x4*)((char*)hstage + n * 1088 + l * 16) = p;
                }
            }
            __syncthreads();   // barrier: stage ready (the only barrier/step)

            const char* ap = (const char*)hstage + (lr & 3) * 1088 + lk * 16;
#pragma unroll
            for (int kk = 0; kk < 16; ++kk) {
                bf16x8 af = *(const bf16x8*)(ap + kk * 64);
                switch (kk & 3) {
                case 0: acc0 = __builtin_amdgcn_mfma_f32_16x16x32_bf16(af, wfrag[kk], acc0, 0, 0, 0); break;
                case 1: acc1 = __builtin_amdgcn_mfma_f32_16x16x32_bf16(af, wfrag[kk], acc1, 0, 0, 0); break;
                case 2: acc2 = __builtin_amdgcn_mfma_f32_16x16x32_bf16(af, wfrag[kk], acc2, 0, 0, 0); break;
                default: acc3 = __builtin_amdgcn_mfma_f32_16x16x32_bf16(af, wfrag[kk], acc3, 0, 0, 0); break;
                }
            }
        } else {
            __syncthreads();   // uniform barrier structure
        }

#pragma unroll
        for (int j = 0; j < 4; ++j)
            acc0[j] += (acc1[j] + acc2[j]) + acc3[j];

        // ---- in-wave cell: activation per gate lane, then 3 shuffles
        const int q = (l >> 2) & 3;
        float av[4];
#pragma unroll
        for (int j = 0; j < 4; ++j)
            av[j] = (q == 2) ? ftanh(acc0[j]) : fsig(acc0[j]);

        float hv[4];
#pragma unroll
        for (int j = 0; j < 4; ++j) {
            float f_ = __shfl_xor(av[j], 4);
            float g_ = __shfl_xor(av[j], 8);
            float o_ = __shfl_xor(av[j], 12);
            c_reg[j] = f_ * c_reg[j] + av[j] * g_;
            hv[j] = o_ * ftanh(c_reg[j]);
        }

        // ---- publish (lanes 0-3 of every wave: col = col4 + l)
        if (l < 4) {
            unsigned int* rp = ringg + (t & 1) * 2048 + col4 + l;
            const unsigned int tag = ((unsigned int)(t + 1)) << 16;
#pragma unroll
            for (int j = 0; j < 4; ++j) {
                unsigned int hw = tag | (unsigned int)f2bf(hv[j]);
                asm volatile("global_store_dword %0, %1, off sc0 sc1"
                             :: "v"(rp + j * 512), "v"(hw) : "memory");
            }
            float* op = out + (size_t)(g * 4) * T_N * H_N + (size_t)t * H_N + col4 + l;
#pragma unroll
            for (int j = 0; j < 4; ++j)
                op[(size_t)j * T_N * H_N] = hv[j];
            if (t == T_N - 1) {
#pragma unroll
                for (int j = 0; j < 4; ++j) {
                    size_t bi = (size_t)(g * 4 + j) * H_N + col4 + l;
                    hn[bi] = hv[j];
                    cn[bi] = c_reg[j];
                }
            }
        }

        // ---- EARLY ISSUE for step t+1: poll loads + xg loads fly during
        // the remaining tail of this step (and other waves' publishes).
        if (t < T_N - 1) {
            if (tid < 64) {
                const unsigned int* q0 = ringg + (t & 1) * 2048 + l * 8;
                const unsigned int* q1 = q0 + 1024;
                asm volatile(
                    "global_load_dwordx4 %0, %8, off sc0 sc1\n\t"
                    "global_load_dwordx4 %1, %8, off offset:16 sc0 sc1\n\t"
                    "global_load_dwordx4 %2, %8, off offset:2048 sc0 sc1\n\t"
                    "global_load_dwordx4 %3, %8, off offset:2064 sc0 sc1\n\t"
                    "global_load_dwordx4 %4, %9, off sc0 sc1\n\t"
                    "global_load_dwordx4 %5, %9, off offset:16 sc0 sc1\n\t"
                    "global_load_dwordx4 %6, %9, off offset:2048 sc0 sc1\n\t"
                    "global_load_dwordx4 %7, %9, off offset:2064 sc0 sc1"
                    : "=&v"(a[0]), "=&v"(a[1]), "=&v"(a[2]), "=&v"(a[3]),
                      "=&v"(a[4]), "=&v"(a[5]), "=&v"(a[6]), "=&v"(a[7])
                    : "v"(q0), "v"(q1)
                    : "memory");
            }
            const ushort_t* xa = xgp + (size_t)(t + 1) * (B_N * G4H);
#pragma unroll
            for (int j = 0; j < 4; ++j) xw[j] = xa[(size_t)j * G4H];
        }
    }
}

// ---------------------------------------------------------------------------
extern "C" void kernel_launch(void* const* d_in, const int* in_sizes, int n_in,
                              void* d_out, int out_size, void* d_ws, size_t ws_size,
                              hipStream_t stream) {
    (void)in_sizes; (void)n_in; (void)out_size; (void)ws_size;
    const float* x   = (const float*)d_in[0];
    const float* wih = (const float*)d_in[1];
    const float* whh = (const float*)d_in[2];
    const float* bih = (const float*)d_in[3];
    const float* bhh = (const float*)d_in[4];
    float* out = (float*)d_out;
    float* hn  = out + (size_t)B_N * T_N * H_N;
    float* cn  = hn + (size_t)B_N * H_N;

    char* ws = (char*)d_ws;
    // ws layout:
    ushort_t*     xg    = (ushort_t*)    (ws);                  // 134217728 B
    ushort_t*     wihb  = (ushort_t*)    (ws + 167772160);      //   2097152 B
    ushort_t*     whhb  = (ushort_t*)    (ws + 169869312);      //   2097152 B
    float*        bias  = (float*)       (ws + 171966464);      //      8192 B
    unsigned int* ringu = (unsigned int*)(ws + 171974656);      //    131072 B

    prep_kernel<<<2048, 256, 0, stream>>>(wih, whh, bih, bhh,
                                          wihb, whhb, bias, ringu);
    xg_gemm<<<512, 512, 0, stream>>>(x, wihb, bias, xg);
    lstm_rec<<<128, 512, 0, stream>>>(xg, whhb, ringu, out, hn, cn);
}

// Round 12
// 2953.281 us; speedup vs baseline: 1.2062x; 1.2062x over previous
//
#include <hip/hip_runtime.h>
#include <stdint.h>

typedef __attribute__((ext_vector_type(4))) float f32x4;
typedef __attribute__((ext_vector_type(8))) short bf16x8;
typedef __attribute__((ext_vector_type(4))) unsigned int u32x4;
typedef __attribute__((ext_vector_type(2))) unsigned int u32x2;
typedef __attribute__((ext_vector_type(4))) unsigned short u16x4;
typedef unsigned short ushort_t;

#define B_N 32
#define T_N 1024
#define D_N 512
#define H_N 512
#define G4H 2048

__device__ __forceinline__ ushort_t f2bf(float f) {
    union { float f; unsigned int u; } v; v.f = f;
    unsigned int r = v.u + 0x7FFFu + ((v.u >> 16) & 1u);   // RNE
    return (ushort_t)(r >> 16);
}
__device__ __forceinline__ float bf2f(ushort_t b) {
    union { unsigned int u; float f; } v; v.u = ((unsigned int)b) << 16;
    return v.f;
}
// fast sigmoid/tanh via v_exp_f32 + v_rcp_f32 (~1e-6 rel err << bf16 eps)
__device__ __forceinline__ float fsig(float x) {
    return __builtin_amdgcn_rcpf(1.f + __expf(-x));
}
__device__ __forceinline__ float ftanh(float x) {
    return 1.f - 2.f * __builtin_amdgcn_rcpf(1.f + __expf(2.f * x));
}

// ---------------------------------------------------------------------------
// prep: fp32 -> bf16 of W_ih, W_hh; bias_sum; zero tagged ring EVERY launch
// (ws persists across graph replays; stale tags would corrupt this run).
// ---------------------------------------------------------------------------
__global__ __launch_bounds__(256) void prep_kernel(
    const float* __restrict__ wih, const float* __restrict__ whh,
    const float* __restrict__ bih, const float* __restrict__ bhh,
    ushort_t* __restrict__ wihb, ushort_t* __restrict__ whhb,
    float* __restrict__ bias, unsigned int* __restrict__ ringu)
{
    size_t i = (size_t)blockIdx.x * 256 + threadIdx.x;
    if (i < 2048) bias[i] = bih[i] + bhh[i];
    if (i < 32768) ringu[i] = 0u;                    // tag 0 = never valid
    const size_t NW = (size_t)G4H * D_N / 4;         // 262144 quads
    if (i < NW) {
        f32x4 v = ((const f32x4*)wih)[i];
        u16x4 o; o[0]=f2bf(v[0]); o[1]=f2bf(v[1]); o[2]=f2bf(v[2]); o[3]=f2bf(v[3]);
        ((u16x4*)wihb)[i] = o;
    } else if (i < 2 * NW) {
        size_t j = i - NW;
        f32x4 v = ((const f32x4*)whh)[j];
        u16x4 o; o[0]=f2bf(v[0]); o[1]=f2bf(v[1]); o[2]=f2bf(v[2]); o[3]=f2bf(v[3]);
        ((u16x4*)whhb)[j] = o;
    }
}

// ---------------------------------------------------------------------------
// xg = x @ W_ih^T + (b_ih+b_hh), stored bf16 as [T][B][4H]. (unchanged R10)
// ---------------------------------------------------------------------------
__global__ __launch_bounds__(512, 1) void xg_gemm(
    const float* __restrict__ x,        // [B][T][D] fp32
    const ushort_t* __restrict__ wihb,  // [4H][D] bf16
    const float* __restrict__ bias,     // [4H]
    ushort_t* __restrict__ xg)          // [T][B][4H] bf16
{
    const int tc = blockIdx.x >> 3;     // 0..63  (t-chunk of 16)
    const int gb = blockIdx.x & 7;      // 0..7   (gate-chunk of 256)
    const int tid = threadIdx.x;
    const int w = tid >> 6, l = tid & 63, lr = l & 15, lk = l >> 4;

    __shared__ ushort_t xs[16 * 520];   // 16 t-rows x 512 d (+8 pad) bf16

    const int r0 = gb * 256 + w * 16;
    const int r1 = r0 + 128;
    bf16x8 a0[16], a1[16];
#pragma unroll
    for (int kk = 0; kk < 16; ++kk) {
        a0[kk] = *(const bf16x8*)(wihb + (size_t)(r0 + lr) * D_N + kk * 32 + lk * 8);
        a1[kk] = *(const bf16x8*)(wihb + (size_t)(r1 + lr) * D_N + kk * 32 + lk * 8);
    }
    float bs0[4], bs1[4];
#pragma unroll
    for (int j = 0; j < 4; ++j) {
        bs0[j] = bias[r0 + lk * 4 + j];
        bs1[j] = bias[r1 + lk * 4 + j];
    }

    const int srow = tid >> 5;          // 0..15 (staging row = t-offset)
    const int sq   = tid & 31;          // 0..31

    for (int b = 0; b < B_N; ++b) {
        const float* xr = x + ((size_t)b * T_N + tc * 16 + srow) * D_N;
#pragma unroll
        for (int c = 0; c < 4; ++c) {
            f32x4 v = *(const f32x4*)(xr + c * 128 + sq * 4);
            u16x4 o; o[0]=f2bf(v[0]); o[1]=f2bf(v[1]); o[2]=f2bf(v[2]); o[3]=f2bf(v[3]);
            *(u16x4*)(xs + srow * 520 + c * 128 + sq * 4) = o;
        }
        __syncthreads();

        f32x4 c0, c1;
#pragma unroll
        for (int j = 0; j < 4; ++j) { c0[j] = 0.f; c1[j] = 0.f; }
#pragma unroll
        for (int kk = 0; kk < 16; ++kk) {
            bf16x8 bf = *(const bf16x8*)((const char*)xs + lr * 1040 + kk * 64 + lk * 16);
            c0 = __builtin_amdgcn_mfma_f32_16x16x32_bf16(a0[kk], bf, c0, 0, 0, 0);
            c1 = __builtin_amdgcn_mfma_f32_16x16x32_bf16(a1[kk], bf, c1, 0, 0, 0);
        }

        const int t = tc * 16 + lr;
        ushort_t* op = xg + (size_t)t * (B_N * G4H) + (size_t)b * G4H;
        u16x4 o0, o1;
#pragma unroll
        for (int j = 0; j < 4; ++j) {
            o0[j] = f2bf(c0[j] + bs0[j]);
            o1[j] = f2bf(c1[j] + bs1[j]);
        }
        *(u16x4*)(op + r0 + lk * 4) = o0;
        *(u16x4*)(op + r1 + lk * 4) = o1;
        __syncthreads();   // protect LDS before next stage
    }
}

// issue one 8-load tagged-ring set (no wait)
#define POLL_ISSUE(dst, p0, p1)                                              \
    asm volatile(                                                            \
        "global_load_dwordx4 %0, %8, off sc0 sc1\n\t"                        \
        "global_load_dwordx4 %1, %8, off offset:16 sc0 sc1\n\t"              \
        "global_load_dwordx4 %2, %8, off offset:2048 sc0 sc1\n\t"            \
        "global_load_dwordx4 %3, %8, off offset:2064 sc0 sc1\n\t"            \
        "global_load_dwordx4 %4, %9, off sc0 sc1\n\t"                        \
        "global_load_dwordx4 %5, %9, off offset:16 sc0 sc1\n\t"              \
        "global_load_dwordx4 %6, %9, off offset:2048 sc0 sc1\n\t"            \
        "global_load_dwordx4 %7, %9, off offset:2064 sc0 sc1"                \
        : "=&v"(dst[0]), "=&v"(dst[1]), "=&v"(dst[2]), "=&v"(dst[3]),        \
          "=&v"(dst[4]), "=&v"(dst[5]), "=&v"(dst[6]), "=&v"(dst[7])         \
        : "v"(p0), "v"(p1)                                                   \
        : "memory")

// issue set `dst`, then wait until only those 8 remain outstanding; the
// previously-issued set `held` is tied "+v" so the compiler cannot hoist
// its tag-check above the waitcnt (rule #18 hazard).
#define POLL_ISSUE_WAIT8(dst, held, p0, p1)                                  \
    asm volatile(                                                            \
        "global_load_dwordx4 %0, %16, off sc0 sc1\n\t"                       \
        "global_load_dwordx4 %1, %16, off offset:16 sc0 sc1\n\t"             \
        "global_load_dwordx4 %2, %16, off offset:2048 sc0 sc1\n\t"           \
        "global_load_dwordx4 %3, %16, off offset:2064 sc0 sc1\n\t"           \
        "global_load_dwordx4 %4, %17, off sc0 sc1\n\t"                       \
        "global_load_dwordx4 %5, %17, off offset:16 sc0 sc1\n\t"             \
        "global_load_dwordx4 %6, %17, off offset:2048 sc0 sc1\n\t"           \
        "global_load_dwordx4 %7, %17, off offset:2064 sc0 sc1\n\t"           \
        "s_waitcnt vmcnt(8)"                                                 \
        : "=&v"(dst[0]), "=&v"(dst[1]), "=&v"(dst[2]), "=&v"(dst[3]),        \
          "=&v"(dst[4]), "=&v"(dst[5]), "=&v"(dst[6]), "=&v"(dst[7]),        \
          "+v"(held[0]), "+v"(held[1]), "+v"(held[2]), "+v"(held[3]),        \
          "+v"(held[4]), "+v"(held[5]), "+v"(held[6]), "+v"(held[7])         \
        : "v"(p0), "v"(p1)                                                   \
        : "memory")

#define TAGCHK(setv, tp, okv)                                                \
    {                                                                        \
        unsigned int d_ = 0;                                                 \
        _Pragma("unroll")                                                    \
        for (int r_ = 0; r_ < 8; ++r_) {                                     \
            d_ |= (setv[r_][0] ^ (tp)); d_ |= (setv[r_][1] ^ (tp));          \
            d_ |= (setv[r_][2] ^ (tp)); d_ |= (setv[r_][3] ^ (tp));          \
        }                                                                    \
        okv = ((d_ & 0xFFFF0000u) == 0u);                                    \
    }

// ---------------------------------------------------------------------------
// Sequential LSTM recurrence — R10 structure (tagged ring, poller wave,
// in-wave gate exchange, one barrier/step) with a PIPELINED PING-PONG POLL:
// two 8-load sets alternate, issue-spaced by the ~150cy check body;
// `vmcnt(8)` waits only for the older set while the younger flies. Detect
// latency = RT + spacing instead of attempts x RT. Each set is waited-on
// before reuse (no WAW in steady state); the one cross-step pending-set
// reissue race is tag-protected (stale return -> failed check -> retry).
// Plus: 4 MFMA accumulator chains; loop-carried xg prefetch.
// ---------------------------------------------------------------------------
__global__ __launch_bounds__(512, 1) void lstm_rec(
    const ushort_t* __restrict__ xg,    // [T][B][4H] bf16 (bias folded)
    const ushort_t* __restrict__ whhb,  // [4H][H] bf16
    unsigned int* __restrict__ ringu,   // [8 grp][2 par][4 batch][512 col] u32
    float* __restrict__ out,            // [B][T][H]
    float* __restrict__ hn,             // [B][H]
    float* __restrict__ cn)             // [B][H]
{
    const int tid = threadIdx.x;
    const int g = blockIdx.x >> 4;
    const int s = blockIdx.x & 15;
    const int w = tid >> 6, l = tid & 63, lr = l & 15, lk = l >> 4;

    __shared__ ushort_t hstage[4][544];   // packed h(t-1); row stride 1088 B

    // ---- persistent W_hh fragments (B operand)
    const int col4 = s * 32 + w * 4;               // this wave's 4 h-cols
    const int gc = (lr >> 2) * 512 + col4 + (lr & 3);
    bf16x8 wfrag[16];
#pragma unroll
    for (int kk = 0; kk < 16; ++kk)
        wfrag[kk] = *(const bf16x8*)(whhb + (size_t)gc * H_N + kk * 32 + lk * 8);

    float c_reg[4] = {0.f, 0.f, 0.f, 0.f};
    unsigned int* ringg = ringu + g * 4096;
    const ushort_t* xgp = xg + (size_t)(g * 4) * G4H + gc;   // + t*B*4H

    ushort_t xw[4];
#pragma unroll
    for (int j = 0; j < 4; ++j) xw[j] = xgp[(size_t)j * G4H];   // xg(t=0)

    u32x4 pa[8], pb[8];

    for (int t = 0; t < T_N; ++t) {
        f32x4 acc0, acc1, acc2, acc3;
#pragma unroll
        for (int j = 0; j < 4; ++j) {
            acc0[j] = bf2f(xw[j]);
            acc1[j] = 0.f; acc2[j] = 0.f; acc3[j] = 0.f;
        }

        if (t > 0) {
            if (tid < 64) {
                const unsigned int* pp0 = ringg + ((t - 1) & 1) * 2048 + l * 8;
                const unsigned int* pp1 = pp0 + 1024;
                const unsigned int tp = ((unsigned int)t) << 16;
                int useA = 0, ok = 0, guard = 0;

                POLL_ISSUE(pa, pp0, pp1);
                for (;;) {
                    POLL_ISSUE_WAIT8(pb, pa, pp0, pp1);   // wait A, B flies
                    TAGCHK(pa, tp, ok);
                    if (__all(ok)) { useA = 1; break; }
                    POLL_ISSUE_WAIT8(pa, pb, pp0, pp1);   // wait B, A flies
                    TAGCHK(pb, tp, ok);
                    if (__all(ok)) { useA = 0; break; }
                    if ((guard += 2) > (1 << 15)) { useA = 0; break; }
                }

                u32x4 fr[8];
#pragma unroll
                for (int r = 0; r < 8; ++r) fr[r] = useA ? pa[r] : pb[r];

                // ---- pack + stage (wave-contiguous ds_write_b128)
#pragma unroll
                for (int n = 0; n < 4; ++n) {
                    u32x4 p;
                    p[0] = __builtin_amdgcn_perm(fr[2*n][1], fr[2*n][0], 0x05040100u);
                    p[1] = __builtin_amdgcn_perm(fr[2*n][3], fr[2*n][2], 0x05040100u);
                    p[2] = __builtin_amdgcn_perm(fr[2*n+1][1], fr[2*n+1][0], 0x05040100u);
                    p[3] = __builtin_amdgcn_perm(fr[2*n+1][3], fr[2*n+1][2], 0x05040100u);
                    *(u32x4*)((char*)hstage + n * 1088 + l * 16) = p;
                }
            }
            __syncthreads();   // barrier: stage ready (the only barrier/step)

            const char* ap = (const char*)hstage + (lr & 3) * 1088 + lk * 16;
#pragma unroll
            for (int kk = 0; kk < 16; ++kk) {
                bf16x8 af = *(const bf16x8*)(ap + kk * 64);
                switch (kk & 3) {
                case 0: acc0 = __builtin_amdgcn_mfma_f32_16x16x32_bf16(af, wfrag[kk], acc0, 0, 0, 0); break;
                case 1: acc1 = __builtin_amdgcn_mfma_f32_16x16x32_bf16(af, wfrag[kk], acc1, 0, 0, 0); break;
                case 2: acc2 = __builtin_amdgcn_mfma_f32_16x16x32_bf16(af, wfrag[kk], acc2, 0, 0, 0); break;
                default: acc3 = __builtin_amdgcn_mfma_f32_16x16x32_bf16(af, wfrag[kk], acc3, 0, 0, 0); break;
                }
            }
        } else {
            __syncthreads();   // uniform barrier structure
        }

#pragma unroll
        for (int j = 0; j < 4; ++j)
            acc0[j] += (acc1[j] + acc2[j]) + acc3[j];

        // ---- in-wave cell: activation per gate lane, then 3 shuffles
        const int q = (l >> 2) & 3;
        float av[4];
#pragma unroll
        for (int j = 0; j < 4; ++j)
            av[j] = (q == 2) ? ftanh(acc0[j]) : fsig(acc0[j]);

        float hv[4];
#pragma unroll
        for (int j = 0; j < 4; ++j) {
            float f_ = __shfl_xor(av[j], 4);
            float g_ = __shfl_xor(av[j], 8);
            float o_ = __shfl_xor(av[j], 12);
            c_reg[j] = f_ * c_reg[j] + av[j] * g_;
            hv[j] = o_ * ftanh(c_reg[j]);
        }

        // ---- publish (lanes 0-3 of every wave: col = col4 + l)
        if (l < 4) {
            unsigned int* rp = ringg + (t & 1) * 2048 + col4 + l;
            const unsigned int tag = ((unsigned int)(t + 1)) << 16;
#pragma unroll
            for (int j = 0; j < 4; ++j) {
                unsigned int hw = tag | (unsigned int)f2bf(hv[j]);
                asm volatile("global_store_dword %0, %1, off sc0 sc1"
                             :: "v"(rp + j * 512), "v"(hw) : "memory");
            }
            float* op = out + (size_t)(g * 4) * T_N * H_N + (size_t)t * H_N + col4 + l;
#pragma unroll
            for (int j = 0; j < 4; ++j)
                op[(size_t)j * T_N * H_N] = hv[j];
            if (t == T_N - 1) {
#pragma unroll
                for (int j = 0; j < 4; ++j) {
                    size_t bi = (size_t)(g * 4 + j) * H_N + col4 + l;
                    hn[bi] = hv[j];
                    cn[bi] = c_reg[j];
                }
            }
        }

        // ---- xg prefetch for t+1 (plain cached loads; drain under poll)
        if (t < T_N - 1) {
            const ushort_t* xa = xgp + (size_t)(t + 1) * (B_N * G4H);
#pragma unroll
            for (int j = 0; j < 4; ++j) xw[j] = xa[(size_t)j * G4H];
        }
    }
}

// ---------------------------------------------------------------------------
extern "C" void kernel_launch(void* const* d_in, const int* in_sizes, int n_in,
                              void* d_out, int out_size, void* d_ws, size_t ws_size,
                              hipStream_t stream) {
    (void)in_sizes; (void)n_in; (void)out_size; (void)ws_size;
    const float* x   = (const float*)d_in[0];
    const float* wih = (const float*)d_in[1];
    const float* whh = (const float*)d_in[2];
    const float* bih = (const float*)d_in[3];
    const float* bhh = (const float*)d_in[4];
    float* out = (float*)d_out;
    float* hn  = out + (size_t)B_N * T_N * H_N;
    float* cn  = hn + (size_t)B_N * H_N;

    char* ws = (char*)d_ws;
    // ws layout:
    ushort_t*     xg    = (ushort_t*)    (ws);                  // 134217728 B
    ushort_t*     wihb  = (ushort_t*)    (ws + 167772160);      //   2097152 B
    ushort_t*     whhb  = (ushort_t*)    (ws + 169869312);      //   2097152 B
    float*        bias  = (float*)       (ws + 171966464);      //      8192 B
    unsigned int* ringu = (unsigned int*)(ws + 171974656);      //    131072 B

    prep_kernel<<<2048, 256, 0, stream>>>(wih, whh, bih, bhh,
                                          wihb, whhb, bias, ringu);
    xg_gemm<<<512, 512, 0, stream>>>(x, wihb, bias, xg);
    lstm_rec<<<128, 512, 0, stream>>>(xg, whhb, ringu, out, hn, cn);
}

// Round 13
// 2137.511 us; speedup vs baseline: 1.6665x; 1.3816x over previous
//
#include <hip/hip_runtime.h>
#include <stdint.h>

typedef __attribute__((ext_vector_type(4))) float f32x4;
typedef __attribute__((ext_vector_type(8))) short bf16x8;
typedef __attribute__((ext_vector_type(4))) unsigned int u32x4;
typedef __attribute__((ext_vector_type(2))) unsigned int u32x2;
typedef __attribute__((ext_vector_type(4))) unsigned short u16x4;
typedef unsigned short ushort_t;

#define B_N 32
#define T_N 1024
#define D_N 512
#define H_N 512
#define G4H 2048

__device__ __forceinline__ ushort_t f2bf(float f) {
    union { float f; unsigned int u; } v; v.f = f;
    unsigned int r = v.u + 0x7FFFu + ((v.u >> 16) & 1u);   // RNE
    return (ushort_t)(r >> 16);
}
__device__ __forceinline__ float bf2f(ushort_t b) {
    union { unsigned int u; float f; } v; v.u = ((unsigned int)b) << 16;
    return v.f;
}
// fast sigmoid/tanh via v_exp_f32 + v_rcp_f32 (~1e-6 rel err << bf16 eps)
__device__ __forceinline__ float fsig(float x) {
    return __builtin_amdgcn_rcpf(1.f + __expf(-x));
}
__device__ __forceinline__ float ftanh(float x) {
    return 1.f - 2.f * __builtin_amdgcn_rcpf(1.f + __expf(2.f * x));
}

// ---------------------------------------------------------------------------
// prep: fp32 -> bf16 of W_ih, W_hh; bias_sum; zero tagged ring EVERY launch
// (ws persists across graph replays; stale tags would corrupt this run).
// ---------------------------------------------------------------------------
__global__ __launch_bounds__(256) void prep_kernel(
    const float* __restrict__ wih, const float* __restrict__ whh,
    const float* __restrict__ bih, const float* __restrict__ bhh,
    ushort_t* __restrict__ wihb, ushort_t* __restrict__ whhb,
    float* __restrict__ bias, unsigned int* __restrict__ ringu)
{
    size_t i = (size_t)blockIdx.x * 256 + threadIdx.x;
    if (i < 2048) bias[i] = bih[i] + bhh[i];
    if (i < 32768) ringu[i] = 0u;                    // tag 0 = never valid
    const size_t NW = (size_t)G4H * D_N / 4;         // 262144 quads
    if (i < NW) {
        f32x4 v = ((const f32x4*)wih)[i];
        u16x4 o; o[0]=f2bf(v[0]); o[1]=f2bf(v[1]); o[2]=f2bf(v[2]); o[3]=f2bf(v[3]);
        ((u16x4*)wihb)[i] = o;
    } else if (i < 2 * NW) {
        size_t j = i - NW;
        f32x4 v = ((const f32x4*)whh)[j];
        u16x4 o; o[0]=f2bf(v[0]); o[1]=f2bf(v[1]); o[2]=f2bf(v[2]); o[3]=f2bf(v[3]);
        ((u16x4*)whhb)[j] = o;
    }
}

// ---------------------------------------------------------------------------
// xg = x @ W_ih^T + (b_ih+b_hh), stored bf16 as [T][B][4H]. (unchanged R10)
// ---------------------------------------------------------------------------
__global__ __launch_bounds__(512, 1) void xg_gemm(
    const float* __restrict__ x,        // [B][T][D] fp32
    const ushort_t* __restrict__ wihb,  // [4H][D] bf16
    const float* __restrict__ bias,     // [4H]
    ushort_t* __restrict__ xg)          // [T][B][4H] bf16
{
    const int tc = blockIdx.x >> 3;     // 0..63  (t-chunk of 16)
    const int gb = blockIdx.x & 7;      // 0..7   (gate-chunk of 256)
    const int tid = threadIdx.x;
    const int w = tid >> 6, l = tid & 63, lr = l & 15, lk = l >> 4;

    __shared__ ushort_t xs[16 * 520];   // 16 t-rows x 512 d (+8 pad) bf16

    const int r0 = gb * 256 + w * 16;
    const int r1 = r0 + 128;
    bf16x8 a0[16], a1[16];
#pragma unroll
    for (int kk = 0; kk < 16; ++kk) {
        a0[kk] = *(const bf16x8*)(wihb + (size_t)(r0 + lr) * D_N + kk * 32 + lk * 8);
        a1[kk] = *(const bf16x8*)(wihb + (size_t)(r1 + lr) * D_N + kk * 32 + lk * 8);
    }
    float bs0[4], bs1[4];
#pragma unroll
    for (int j = 0; j < 4; ++j) {
        bs0[j] = bias[r0 + lk * 4 + j];
        bs1[j] = bias[r1 + lk * 4 + j];
    }

    const int srow = tid >> 5;          // 0..15 (staging row = t-offset)
    const int sq   = tid & 31;          // 0..31

    for (int b = 0; b < B_N; ++b) {
        const float* xr = x + ((size_t)b * T_N + tc * 16 + srow) * D_N;
#pragma unroll
        for (int c = 0; c < 4; ++c) {
            f32x4 v = *(const f32x4*)(xr + c * 128 + sq * 4);
            u16x4 o; o[0]=f2bf(v[0]); o[1]=f2bf(v[1]); o[2]=f2bf(v[2]); o[3]=f2bf(v[3]);
            *(u16x4*)(xs + srow * 520 + c * 128 + sq * 4) = o;
        }
        __syncthreads();

        f32x4 c0, c1;
#pragma unroll
        for (int j = 0; j < 4; ++j) { c0[j] = 0.f; c1[j] = 0.f; }
#pragma unroll
        for (int kk = 0; kk < 16; ++kk) {
            bf16x8 bf = *(const bf16x8*)((const char*)xs + lr * 1040 + kk * 64 + lk * 16);
            c0 = __builtin_amdgcn_mfma_f32_16x16x32_bf16(a0[kk], bf, c0, 0, 0, 0);
            c1 = __builtin_amdgcn_mfma_f32_16x16x32_bf16(a1[kk], bf, c1, 0, 0, 0);
        }

        const int t = tc * 16 + lr;
        ushort_t* op = xg + (size_t)t * (B_N * G4H) + (size_t)b * G4H;
        u16x4 o0, o1;
#pragma unroll
        for (int j = 0; j < 4; ++j) {
            o0[j] = f2bf(c0[j] + bs0[j]);
            o1[j] = f2bf(c1[j] + bs1[j]);
        }
        *(u16x4*)(op + r0 + lk * 4) = o0;
        *(u16x4*)(op + r1 + lk * 4) = o1;
        __syncthreads();   // protect LDS before next stage
    }
}

// ---------------------------------------------------------------------------
// Sequential LSTM recurrence — the PROVEN R10 sync discipline restored:
// per attempt {issue 8 tagged loads, vmcnt(0), tag-check}, s_sleep(1)
// between failed attempts. R11 (early issue) and R12 (vmcnt(8) ping-pong)
// both regressed: sampling the coherence point faster than ~1 RT period
// congests the fabric and delays the producers' own publishes. Kept from
// R12 (harmless): 4 independent MFMA accumulator chains; xg prefetch at
// loop bottom (HBM latency hides under publish + next poll).
// ---------------------------------------------------------------------------
__global__ __launch_bounds__(512, 1) void lstm_rec(
    const ushort_t* __restrict__ xg,    // [T][B][4H] bf16 (bias folded)
    const ushort_t* __restrict__ whhb,  // [4H][H] bf16
    unsigned int* __restrict__ ringu,   // [8 grp][2 par][4 batch][512 col] u32
    float* __restrict__ out,            // [B][T][H]
    float* __restrict__ hn,             // [B][H]
    float* __restrict__ cn)             // [B][H]
{
    const int tid = threadIdx.x;
    const int g = blockIdx.x >> 4;
    const int s = blockIdx.x & 15;
    const int w = tid >> 6, l = tid & 63, lr = l & 15, lk = l >> 4;

    __shared__ ushort_t hstage[4][544];   // packed h(t-1); row stride 1088 B

    // ---- persistent W_hh fragments (B operand)
    const int col4 = s * 32 + w * 4;               // this wave's 4 h-cols
    const int gc = (lr >> 2) * 512 + col4 + (lr & 3);
    bf16x8 wfrag[16];
#pragma unroll
    for (int kk = 0; kk < 16; ++kk)
        wfrag[kk] = *(const bf16x8*)(whhb + (size_t)gc * H_N + kk * 32 + lk * 8);

    float c_reg[4] = {0.f, 0.f, 0.f, 0.f};
    unsigned int* ringg = ringu + g * 4096;
    const ushort_t* xgp = xg + (size_t)(g * 4) * G4H + gc;   // + t*B*4H

    ushort_t xw[4];
#pragma unroll
    for (int j = 0; j < 4; ++j) xw[j] = xgp[(size_t)j * G4H];   // xg(t=0)

    for (int t = 0; t < T_N; ++t) {
        f32x4 acc0, acc1, acc2, acc3;
#pragma unroll
        for (int j = 0; j < 4; ++j) {
            acc0[j] = bf2f(xw[j]);
            acc1[j] = 0.f; acc2[j] = 0.f; acc3[j] = 0.f;
        }

        if (t > 0) {
            if (tid < 64) {
                // ---- poller wave: validate + stage h(t-1)  (R10 discipline)
                const unsigned int* pp0 = ringg + ((t - 1) & 1) * 2048 + l * 8;
                const unsigned int* pp1 = pp0 + 1024;
                const unsigned int tp = ((unsigned int)t) << 16;
                u32x4 a[8];
                int guard = 0;
                for (;;) {
                    asm volatile(
                        "global_load_dwordx4 %0, %8, off sc0 sc1\n\t"
                        "global_load_dwordx4 %1, %8, off offset:16 sc0 sc1\n\t"
                        "global_load_dwordx4 %2, %8, off offset:2048 sc0 sc1\n\t"
                        "global_load_dwordx4 %3, %8, off offset:2064 sc0 sc1\n\t"
                        "global_load_dwordx4 %4, %9, off sc0 sc1\n\t"
                        "global_load_dwordx4 %5, %9, off offset:16 sc0 sc1\n\t"
                        "global_load_dwordx4 %6, %9, off offset:2048 sc0 sc1\n\t"
                        "global_load_dwordx4 %7, %9, off offset:2064 sc0 sc1\n\t"
                        "s_waitcnt vmcnt(0)"
                        : "=&v"(a[0]), "=&v"(a[1]), "=&v"(a[2]), "=&v"(a[3]),
                          "=&v"(a[4]), "=&v"(a[5]), "=&v"(a[6]), "=&v"(a[7])
                        : "v"(pp0), "v"(pp1)
                        : "memory");
                    unsigned int d = 0;
#pragma unroll
                    for (int r = 0; r < 8; ++r) {
                        d |= (a[r][0] ^ tp); d |= (a[r][1] ^ tp);
                        d |= (a[r][2] ^ tp); d |= (a[r][3] ^ tp);
                    }
                    int ok = ((d & 0xFFFF0000u) == 0u);
                    if (__all(ok) || ++guard > (1 << 16)) break;
                    __builtin_amdgcn_s_sleep(1);   // throttle: >= ~1 RT period
                }
                // ---- pack + stage (wave-contiguous ds_write_b128)
#pragma unroll
                for (int n = 0; n < 4; ++n) {
                    u32x4 p;
                    p[0] = __builtin_amdgcn_perm(a[2*n][1], a[2*n][0], 0x05040100u);
                    p[1] = __builtin_amdgcn_perm(a[2*n][3], a[2*n][2], 0x05040100u);
                    p[2] = __builtin_amdgcn_perm(a[2*n+1][1], a[2*n+1][0], 0x05040100u);
                    p[3] = __builtin_amdgcn_perm(a[2*n+1][3], a[2*n+1][2], 0x05040100u);
                    *(u32x4*)((char*)hstage + n * 1088 + l * 16) = p;
                }
            }
            __syncthreads();   // barrier: stage ready (the only barrier/step)

            const char* ap = (const char*)hstage + (lr & 3) * 1088 + lk * 16;
#pragma unroll
            for (int kk = 0; kk < 16; ++kk) {
                bf16x8 af = *(const bf16x8*)(ap + kk * 64);
                switch (kk & 3) {
                case 0: acc0 = __builtin_amdgcn_mfma_f32_16x16x32_bf16(af, wfrag[kk], acc0, 0, 0, 0); break;
                case 1: acc1 = __builtin_amdgcn_mfma_f32_16x16x32_bf16(af, wfrag[kk], acc1, 0, 0, 0); break;
                case 2: acc2 = __builtin_amdgcn_mfma_f32_16x16x32_bf16(af, wfrag[kk], acc2, 0, 0, 0); break;
                default: acc3 = __builtin_amdgcn_mfma_f32_16x16x32_bf16(af, wfrag[kk], acc3, 0, 0, 0); break;
                }
            }
        } else {
            __syncthreads();   // uniform barrier structure
        }

#pragma unroll
        for (int j = 0; j < 4; ++j)
            acc0[j] += (acc1[j] + acc2[j]) + acc3[j];

        // ---- in-wave cell: activation per gate lane, then 3 shuffles
        const int q = (l >> 2) & 3;
        float av[4];
#pragma unroll
        for (int j = 0; j < 4; ++j)
            av[j] = (q == 2) ? ftanh(acc0[j]) : fsig(acc0[j]);

        float hv[4];
#pragma unroll
        for (int j = 0; j < 4; ++j) {
            float f_ = __shfl_xor(av[j], 4);
            float g_ = __shfl_xor(av[j], 8);
            float o_ = __shfl_xor(av[j], 12);
            c_reg[j] = f_ * c_reg[j] + av[j] * g_;
            hv[j] = o_ * ftanh(c_reg[j]);
        }

        // ---- publish (lanes 0-3 of every wave: col = col4 + l)
        if (l < 4) {
            unsigned int* rp = ringg + (t & 1) * 2048 + col4 + l;
            const unsigned int tag = ((unsigned int)(t + 1)) << 16;
#pragma unroll
            for (int j = 0; j < 4; ++j) {
                unsigned int hw = tag | (unsigned int)f2bf(hv[j]);
                asm volatile("global_store_dword %0, %1, off sc0 sc1"
                             :: "v"(rp + j * 512), "v"(hw) : "memory");
            }
            float* op = out + (size_t)(g * 4) * T_N * H_N + (size_t)t * H_N + col4 + l;
#pragma unroll
            for (int j = 0; j < 4; ++j)
                op[(size_t)j * T_N * H_N] = hv[j];
            if (t == T_N - 1) {
#pragma unroll
                for (int j = 0; j < 4; ++j) {
                    size_t bi = (size_t)(g * 4 + j) * H_N + col4 + l;
                    hn[bi] = hv[j];
                    cn[bi] = c_reg[j];
                }
            }
        }

        // ---- xg prefetch for t+1 (plain cached loads; latency hides under
        // the publish tail and next step's poll)
        if (t < T_N - 1) {
            const ushort_t* xa = xgp + (size_t)(t + 1) * (B_N * G4H);
#pragma unroll
            for (int j = 0; j < 4; ++j) xw[j] = xa[(size_t)j * G4H];
        }
    }
}

// ---------------------------------------------------------------------------
extern "C" void kernel_launch(void* const* d_in, const int* in_sizes, int n_in,
                              void* d_out, int out_size, void* d_ws, size_t ws_size,
                              hipStream_t stream) {
    (void)in_sizes; (void)n_in; (void)out_size; (void)ws_size;
    const float* x   = (const float*)d_in[0];
    const float* wih = (const float*)d_in[1];
    const float* whh = (const float*)d_in[2];
    const float* bih = (const float*)d_in[3];
    const float* bhh = (const float*)d_in[4];
    float* out = (float*)d_out;
    float* hn  = out + (size_t)B_N * T_N * H_N;
    float* cn  = hn + (size_t)B_N * H_N;

    char* ws = (char*)d_ws;
    // ws layout:
    ushort_t*     xg    = (ushort_t*)    (ws);                  // 134217728 B
    ushort_t*     wihb  = (ushort_t*)    (ws + 167772160);      //   2097152 B
    ushort_t*     whhb  = (ushort_t*)    (ws + 169869312);      //   2097152 B
    float*        bias  = (float*)       (ws + 171966464);      //      8192 B
    unsigned int* ringu = (unsigned int*)(ws + 171974656);      //    131072 B

    prep_kernel<<<2048, 256, 0, stream>>>(wih, whh, bih, bhh,
                                          wihb, whhb, bias, ringu);
    xg_gemm<<<512, 512, 0, stream>>>(x, wihb, bias, xg);
    lstm_rec<<<128, 512, 0, stream>>>(xg, whhb, ringu, out, hn, cn);
}